// Round 13
// baseline (1398.029 us; speedup 1.0000x reference)
//
#include <hip/hip_runtime.h>
#include <hip/hip_fp16.h>
#include <stdint.h>

typedef __attribute__((ext_vector_type(8)))  _Float16 f16x8;
typedef __attribute__((ext_vector_type(4)))  _Float16 f16x4;
typedef __attribute__((ext_vector_type(4)))  float    f32x4;

#define MFMA16 __builtin_amdgcn_mfma_f32_16x16x32_f16

__device__ __forceinline__ void split4(const f32x4 v, f16x4 &h, f16x4 &l) {
    #pragma unroll
    for (int i = 0; i < 4; ++i) {
        float a = v[i];
        _Float16 hh = (_Float16)a;        // v_cvt_f16_f32 (RNE)
        h[i] = hh;
        l[i] = (_Float16)(a - (float)hh); // residual, rel err ~2^-24
    }
}

// ========== pack: f32 [rows x 4096] -> fragment-major f16 hi/lo planes ==========
// dst[((rg*128 + kg)*64 + lane)*8 + e] = split(src[rg*16 + (lane&15)][kg*32 + (lane>>4)*8 + e])
// Per-lane data identical to the LDS path (XOR swizzle cancels for 16-aligned rows),
// so GEMM numerics are unchanged. Wave-tile writes are contiguous 1KB (coalesced).
__global__ __launch_bounds__(256)
void pack_frag(const float* __restrict__ src, _Float16* __restrict__ h,
               _Float16* __restrict__ l, int srcRows, int nTiles)
{
    const int lane = threadIdx.x & 63;
    const int fr = lane & 15, fg = lane >> 4;
    const int w  = (blockIdx.x * 256 + threadIdx.x) >> 6;
    const int nw = (gridDim.x * 256) >> 6;
    for (int t = w; t < nTiles; t += nw) {
        const int rg  = t >> 7;           // / KG(=128)
        const int kg  = t & 127;
        const int row = rg * 16 + fr;
        const int kb  = kg * 32 + fg * 8;
        f32x4 v0 = {}, v1 = {};
        if (row < srcRows) {
            v0 = *(const f32x4*)(src + (size_t)row * 4096 + kb);
            v1 = *(const f32x4*)(src + (size_t)row * 4096 + kb + 4);
        }
        f16x4 h0, l0, h1, l1;
        split4(v0, h0, l0);
        split4(v1, h1, l1);
        f16x8 hh, ll;
        #pragma unroll
        for (int i = 0; i < 4; ++i) { hh[i] = h0[i]; hh[4+i] = h1[i]; ll[i] = l0[i]; ll[4+i] = l1[i]; }
        const size_t o = ((size_t)t * 64 + lane) * 8;
        *(f16x8*)(h + o) = hh;
        *(f16x8*)(l + o) = ll;
    }
}

// ========== split-3 GEMM v13: zero-LDS, fragment-packed operands ==========
// C[m][n] = act( sum_k A[m][k]*B[n][k] + bias[n] ), A/B fragment-packed hi/lo.
// BM = MI*32, BN = 256, 8 waves (2M x 4N). Per K-step each wave does 24 coalesced
// 1KB global loads (SGPR base + 32b voffset, +1024B/step) + 96 MFMAs. No LDS,
// no barriers, no staging: the DS-pipe tax (R5-R11: ~3000cyc/step serial with
// MFMA's 3725 -> 57% pin) is gone. A-frags read 4x redundantly across wn-waves
// from L2 (~1400cyc/step/CU equivalent, hidden). Compiler handles vmcnt.
template<int MI, bool SPLITOUT, bool CHUNKSWZ>
__global__ __launch_bounds__(512)
void gemm_pack(const _Float16* __restrict__ Agh, const _Float16* __restrict__ Agl,
               const _Float16* __restrict__ Bgh, const _Float16* __restrict__ Bgl,
               const float* __restrict__ bias,
               _Float16* __restrict__ Oh, _Float16* __restrict__ Ol,
               float* __restrict__ Of, int Nstore, int nBN)
{
    constexpr int KG    = 128;           // 4096 / 32
    constexpr int WROWS = MI * 16;
    constexpr int BM    = MI * 32;

    const int tid  = threadIdx.x;
    const int lane = tid & 63;
    const int wave = tid >> 6;
    const int wm = wave >> 2;
    const int wn = wave & 3;
    const int fr = lane & 15;
    const int fg = lane >> 4;

    // ---- block swizzle (proven R5/R11 maps) ----
    int bm, bn;
    const int orig = blockIdx.x;
    if (CHUNKSWZ) {
        // GEMM1: 512 blocks = 32bm x 16bn; XCD k owns bm in [4k,4k+4), bn sweeping.
        bm = ((orig & 7) << 2) | ((orig >> 3) & 3);
        bn = orig >> 5;
    } else {
        // bn-inner: each XCD sweeps all bn for a contiguous bm range
        const int cpx  = gridDim.x >> 3;
        const int swzb = (orig & 7) * cpx + (orig >> 3);
        bn = swzb % nBN;
        bm = swzb / nBN;
    }
    const int m0 = bm * BM;
    const int n0 = bn * 256;

    // ---- fragment voffsets (bytes); +1024 per K-step ----
    const int rgA0 = (m0 >> 4) + wm * MI;
    const int rgB0 = (n0 >> 4) + wn * 4;
    uint32_t aoff[MI], boff[4];
    #pragma unroll
    for (int mi = 0; mi < MI; ++mi) aoff[mi] = (uint32_t)(((rgA0 + mi) * KG) * 64 + lane) * 16u;
    #pragma unroll
    for (int ni = 0; ni < 4; ++ni)  boff[ni] = (uint32_t)(((rgB0 + ni) * KG) * 64 + lane) * 16u;

    f32x4 acc[MI][4] = {};

    for (int t = 0; t < KG; ++t) {
        f16x8 ah[MI], al[MI], bh[4], bl[4];
        #pragma unroll
        for (int ni = 0; ni < 4; ++ni) {
            bh[ni] = *(const f16x8*)((const char*)Bgh + boff[ni]);
            bl[ni] = *(const f16x8*)((const char*)Bgl + boff[ni]);
            boff[ni] += 1024;
        }
        #pragma unroll
        for (int mi = 0; mi < MI; ++mi) {
            ah[mi] = *(const f16x8*)((const char*)Agh + aoff[mi]);
            al[mi] = *(const f16x8*)((const char*)Agl + aoff[mi]);
            aoff[mi] += 1024;
        }
        #pragma unroll
        for (int mi = 0; mi < MI; ++mi) {
            #pragma unroll
            for (int ni = 0; ni < 4; ++ni) acc[mi][ni] = MFMA16(ah[mi], bh[ni], acc[mi][ni], 0, 0, 0);
            #pragma unroll
            for (int ni = 0; ni < 4; ++ni) acc[mi][ni] = MFMA16(ah[mi], bl[ni], acc[mi][ni], 0, 0, 0);
            #pragma unroll
            for (int ni = 0; ni < 4; ++ni) acc[mi][ni] = MFMA16(al[mi], bh[ni], acc[mi][ni], 0, 0, 0);
        }
    }

    // ---- epilogue ----
    // 16x16 D mapping (HW-verified): n = lane&15, m = (lane>>4)*4 + reg
    #pragma unroll
    for (int ni = 0; ni < 4; ++ni) {
        const int n = n0 + wn*64 + ni*16 + fr;
        if (!SPLITOUT && n >= Nstore) continue;
        const float bv = bias[n];
        if (SPLITOUT) {
            // write act fragment-packed (act is GEMM2's A: rowdim=m, kdim=n)
            const int    kg_a = n >> 5;
            const int    lb_a = ((n >> 3) & 3) * 16;   // fg_act*16
            const int    e_a  = n & 7;
            #pragma unroll
            for (int mi = 0; mi < MI; ++mi) {
                #pragma unroll
                for (int j = 0; j < 4; ++j) {
                    const int m = m0 + wm*WROWS + mi*16 + fg*4 + j;
                    float v = fmaxf(acc[mi][ni][j] + bv, 0.f);
                    const _Float16 hh = (_Float16)v;
                    const size_t o = (((size_t)(m >> 4) * KG + kg_a) * 64 + lb_a + (m & 15)) * 8 + e_a;
                    Oh[o] = hh;
                    Ol[o] = (_Float16)(v - (float)hh);
                }
            }
        } else {
            #pragma unroll
            for (int mi = 0; mi < MI; ++mi) {
                #pragma unroll
                for (int j = 0; j < 4; ++j) {
                    const int m = m0 + wm*WROWS + mi*16 + fg*4 + j;
                    Of[(size_t)m * Nstore + n] = acc[mi][ni][j] + bv;
                }
            }
        }
    }
}

// ================= fallback path (R2, known-passing) =================
#define TILE_M 128
#define TILE_N 128
#define TILE_K 32
#define LDSK   40

template<bool RELU, bool NGUARD>
__global__ __launch_bounds__(256, 2)
void gemm_split3(const float* __restrict__ A, const float* __restrict__ B,
                 const float* __restrict__ bias, float* __restrict__ C,
                 int K, int ldc, int Nreal)
{
    __shared__ _Float16 Ah[TILE_M][LDSK];
    __shared__ _Float16 Al[TILE_M][LDSK];
    __shared__ _Float16 Bh[TILE_N][LDSK];
    __shared__ _Float16 Bl[TILE_N][LDSK];

    const int tid  = threadIdx.x;
    const int lane = tid & 63;
    const int wave = tid >> 6;
    const int wr   = wave >> 1;
    const int wc   = wave & 1;
    const int m0   = blockIdx.x * TILE_M;
    const int n0   = blockIdx.y * TILE_N;
    const int srow = tid >> 3;
    const int scol = (tid & 7) << 2;
    const int fr = lane & 15;
    const int fg = lane >> 4;

    f32x4 acc[4][4] = {};

    for (int kt = 0; kt < K; kt += TILE_K) {
        __syncthreads();
        #pragma unroll
        for (int p = 0; p < 4; ++p) {
            const int row = srow + p * 32;
            f32x4 v = *(const f32x4*)(A + (size_t)(m0 + row) * K + kt + scol);
            f16x4 hv, lv;
            split4(v, hv, lv);
            *(f16x4*)&Ah[row][scol] = hv;
            *(f16x4*)&Al[row][scol] = lv;
        }
        #pragma unroll
        for (int p = 0; p < 4; ++p) {
            const int row = srow + p * 32;
            f32x4 v = {0.f, 0.f, 0.f, 0.f};
            if (!NGUARD || (n0 + row) < Nreal)
                v = *(const f32x4*)(B + (size_t)(n0 + row) * K + kt + scol);
            f16x4 hv, lv;
            split4(v, hv, lv);
            *(f16x4*)&Bh[row][scol] = hv;
            *(f16x4*)&Bl[row][scol] = lv;
        }
        __syncthreads();

        f16x8 ah[4], al[4];
        #pragma unroll
        for (int mi = 0; mi < 4; ++mi) {
            const int r = wr * 64 + mi * 16 + fr;
            ah[mi] = *(const f16x8*)&Ah[r][fg * 8];
            al[mi] = *(const f16x8*)&Al[r][fg * 8];
        }
        #pragma unroll
        for (int ni = 0; ni < 4; ++ni) {
            const int r = wc * 64 + ni * 16 + fr;
            const f16x8 bh = *(const f16x8*)&Bh[r][fg * 8];
            const f16x8 bl = *(const f16x8*)&Bl[r][fg * 8];
            #pragma unroll
            for (int mi = 0; mi < 4; ++mi) {
                acc[mi][ni] = MFMA16(ah[mi], bh, acc[mi][ni], 0, 0, 0);
                acc[mi][ni] = MFMA16(ah[mi], bl, acc[mi][ni], 0, 0, 0);
                acc[mi][ni] = MFMA16(al[mi], bh, acc[mi][ni], 0, 0, 0);
            }
        }
    }

    #pragma unroll
    for (int ni = 0; ni < 4; ++ni) {
        const int n = n0 + wc * 64 + ni * 16 + fr;
        if (NGUARD && n >= Nreal) continue;
        const float bv = bias[n];
        #pragma unroll
        for (int mi = 0; mi < 4; ++mi) {
            #pragma unroll
            for (int j = 0; j < 4; ++j) {
                const int m = m0 + wr * 64 + mi * 16 + fg * 4 + j;
                float val = acc[mi][ni][j] + bv;
                if (RELU) val = fmaxf(val, 0.f);
                C[(size_t)m * ldc + n] = val;
            }
        }
    }
}

// In-place row softmax: one wave per row (cols <= 1024).
__global__ __launch_bounds__(256)
void softmax_rows(float* __restrict__ out, int rows, int cols)
{
    const int lane = threadIdx.x & 63;
    const int row  = blockIdx.x * 4 + (threadIdx.x >> 6);
    if (row >= rows) return;
    float* p = out + (size_t)row * cols;

    float v[16];
    float mx = -3.4e38f;
    #pragma unroll
    for (int j = 0; j < 16; ++j) {
        const int c = lane + j * 64;
        v[j] = (c < cols) ? p[c] : -3.4e38f;
        mx = fmaxf(mx, v[j]);
    }
    #pragma unroll
    for (int off = 32; off > 0; off >>= 1)
        mx = fmaxf(mx, __shfl_xor(mx, off));

    float s = 0.f;
    #pragma unroll
    for (int j = 0; j < 16; ++j) {
        const int c = lane + j * 64;
        const float e = (c < cols) ? __expf(v[j] - mx) : 0.f;
        v[j] = e;
        s += e;
    }
    #pragma unroll
    for (int off = 32; off > 0; off >>= 1)
        s += __shfl_xor(s, off);

    const float inv = 1.f / s;
    #pragma unroll
    for (int j = 0; j < 16; ++j) {
        const int c = lane + j * 64;
        if (c < cols) p[c] = v[j] * inv;
    }
}

// ================= host =================
extern "C" void kernel_launch(void* const* d_in, const int* in_sizes, int n_in,
                              void* d_out, int out_size, void* d_ws, size_t ws_size,
                              hipStream_t stream)
{
    const float* x  = (const float*)d_in[0];   // [8192, 4096]
    const float* w1 = (const float*)d_in[1];   // [4096, 4096]
    const float* b1 = (const float*)d_in[2];   // [4096]
    const float* w2 = (const float*)d_in[3];   // [1000, 4096]
    const float* b2 = (const float*)d_in[4];   // [1000]
    float* out = (float*)d_out;                // [8192, 1000] fp32

    const size_t SZ_X  = (size_t)8192 * 4096 * 2;   // one plane (packed, same bytes)
    const size_t SZ_W1 = (size_t)4096 * 4096 * 2;
    const size_t SZ_W2 = (size_t)1024 * 4096 * 2;

    size_t off = 0;
    auto take = [&](size_t b) { size_t o = off; off += (b + 255) & ~(size_t)255; return o; };
    const size_t o_xh  = take(SZ_X),  o_xl  = take(SZ_X);
    const size_t o_w1h = take(SZ_W1), o_w1l = take(SZ_W1);
    const size_t o_w2h = take(SZ_W2), o_w2l = take(SZ_W2);
    const size_t o_ah  = take(SZ_X),  o_al  = take(SZ_X);
    const size_t need = off;

    const dim3 blk256(256, 1, 1), blk512(512, 1, 1);

    if (ws_size >= need) {
        char* w = (char*)d_ws;
        _Float16 *xh  = (_Float16*)(w + o_xh),  *xl  = (_Float16*)(w + o_xl);
        _Float16 *w1h = (_Float16*)(w + o_w1h), *w1l = (_Float16*)(w + o_w1l);
        _Float16 *w2h = (_Float16*)(w + o_w2h), *w2l = (_Float16*)(w + o_w2l);
        _Float16 *ath = (_Float16*)(w + o_ah),  *atl = (_Float16*)(w + o_al);

        // pack all operands fragment-major (BW-bound; same bytes as the old splits)
        hipLaunchKernelGGL(pack_frag, dim3(2048), blk256, 0, stream, x,  xh,  xl,  8192, 512 * 128);
        hipLaunchKernelGGL(pack_frag, dim3(2048), blk256, 0, stream, w1, w1h, w1l, 4096, 256 * 128);
        hipLaunchKernelGGL(pack_frag, dim3(512),  blk256, 0, stream, w2, w2h, w2l, 1000, 64 * 128);

        // GEMM1: act(packed hi/lo) = relu(x @ w1^T + b1)  M=8192 N=4096 K=4096
        // grid 512 = 32bm x 16bn, chunked XCD swizzle, BM=256
        hipLaunchKernelGGL((gemm_pack<8, true, true>), dim3(512), blk512, 0, stream,
                           xh, xl, w1h, w1l, b1, ath, atl, (float*)nullptr, 4096, 16);
        // GEMM2: logits = act @ w2^T + b2   M=8192 N=1024(pad, guard 1000) K=4096
        // grid 256 = 64bm x 4bn, bn-inner, BM=128
        hipLaunchKernelGGL((gemm_pack<4, false, false>), dim3(256), blk512, 0, stream,
                           ath, atl, w2h, w2l, b2, (_Float16*)nullptr, (_Float16*)nullptr,
                           out, 1000, 4);
        hipLaunchKernelGGL(softmax_rows, dim3(2048), blk256, 0, stream, out, 8192, 1000);
    } else {
        float* act = (float*)d_ws;
        hipLaunchKernelGGL((gemm_split3<true, false>), dim3(64, 32), blk256, 0, stream,
                           x, w1, b1, act, 4096, 4096, 4096);
        hipLaunchKernelGGL((gemm_split3<false, true>), dim3(64, 8), blk256, 0, stream,
                           act, w2, b2, out, 4096, 1000, 1000);
        hipLaunchKernelGGL(softmax_rows, dim3(2048), blk256, 0, stream, out, 8192, 1000);
    }
}

// Round 14
// 932.061 us; speedup vs baseline: 1.4999x; 1.4999x over previous
//
#include <hip/hip_runtime.h>
#include <hip/hip_fp16.h>
#include <stdint.h>

typedef __attribute__((ext_vector_type(8)))  _Float16 f16x8;
typedef __attribute__((ext_vector_type(4)))  _Float16 f16x4;
typedef __attribute__((ext_vector_type(4)))  float    f32x4;

__device__ __forceinline__ void split4(const f32x4 v, f16x4 &h, f16x4 &l) {
    #pragma unroll
    for (int i = 0; i < 4; ++i) {
        float a = v[i];
        _Float16 hh = (_Float16)a;        // v_cvt_f16_f32 (RNE)
        h[i] = hh;
        l[i] = (_Float16)(a - (float)hh); // residual, rel err ~2^-24
    }
}

// ================= pre-split: f32 [rows x 4096] -> f16 hi/lo planes =================
__global__ __launch_bounds__(256)
void split_rows(const float* __restrict__ src, _Float16* __restrict__ h,
                _Float16* __restrict__ l, int srcRows, long long total4)
{
    const long long stride = (long long)gridDim.x * blockDim.x;
    for (long long i = (long long)blockIdx.x * blockDim.x + threadIdx.x; i < total4; i += stride) {
        const long long e = i << 2;
        const int row = (int)(e >> 12);      // cols = 4096
        f16x4 hv = {}, lv = {};
        if (row < srcRows) {
            f32x4 v = *(const f32x4*)(src + e);
            split4(v, hv, lv);
        }
        *(f16x4*)(h + e) = hv;
        *(f16x4*)(l + e) = lv;
    }
}

// ================= split-3 GEMM v11: distance-1 read-use schedule =================
// C[m][n] = act( sum_k A[m][k]*B[n][k] + bias[n] ), A/B as f16 hi/lo planes.
// BM = MI*32, BN = 256, BK = 32, 8 waves (2M x 4N), dbuf LDS, 1 barrier/step.
// EVERY ds_read is consumed one MFMA-group later (>=6 MFMAs distance), so the
// compiler's fine-grained lgkmcnt never forces a 0-distance stall:
//   pre: {b0,b1,a0}  G0: {rd b2,b3 | 6 MFMA}  G1: {rd a1 | 6 MFMA}
//   G2..G(MI): {rd a(mi+1) | 12 MFMA product-major}
// Zero-conflict 16-row-span LDS patterns (R3/R5/R8-verified, 32-row span refuted).
// NOTE (R12/R13): moving operand traffic off LDS to global (reg-gather or packed
// coalesced) regresses 1.4-1.5x -- LDS+global_load_lds IS the best delivery path;
// its ~3000cyc/step is additive with MFMA's 3725 (57% pin, structure-converged).

#define BARRIER() __builtin_amdgcn_s_barrier()
#define SB0()     __builtin_amdgcn_sched_barrier(0)
#define MFMA16    __builtin_amdgcn_mfma_f32_16x16x32_f16
#define SGB       __builtin_amdgcn_sched_group_barrier

template<int N> __device__ __forceinline__ void VMCNT() {
    asm volatile("s_waitcnt vmcnt(%0)" :: "n"(N) : "memory");
    __builtin_amdgcn_sched_barrier(0);
}

__device__ __forceinline__ void gload16(const _Float16* g, _Float16* l) {
    __builtin_amdgcn_global_load_lds(
        (const __attribute__((address_space(1))) void*)g,
        (__attribute__((address_space(3))) void*)l, 16, 0, 0);
}

template<int MI, bool SPLITOUT, bool CHUNKSWZ>
__global__ __launch_bounds__(512, 2)
void gemm3_v11(const _Float16* __restrict__ Agh, const _Float16* __restrict__ Agl,
               const _Float16* __restrict__ Bgh, const _Float16* __restrict__ Bgl,
               const float* __restrict__ bias,
               _Float16* __restrict__ Oh, _Float16* __restrict__ Ol,
               float* __restrict__ Of, int ldo, int Nstore,
               int K, int nBN)
{
    extern __shared__ _Float16 lds[];
    constexpr int WROWS = MI * 16;
    constexpr int BM    = MI * 32;
    constexpr int CHA   = MI * 2;            // 1KB chunks per A plane
    constexpr int PW    = (2*CHA + 32) / 8;  // chunks per wave (8 or 6)
    constexpr int H1    = PW - CHA/8;
    constexpr int H2    = CHA / 8;
    constexpr int ALO   = CHA * 512;
    constexpr int BHO   = 2 * CHA * 512;
    constexpr int BUFS  = 2*CHA*512 + 16384;

    const int tid  = threadIdx.x;
    const int lane = tid & 63;
    const int wave = tid >> 6;
    const int wm = wave >> 2;
    const int wn = wave & 3;
    const int fr = lane & 15;
    const int fg = lane >> 4;

    // ---- block swizzle ----
    int bm, bn;
    const int orig = blockIdx.x;
    if (CHUNKSWZ) {
        // GEMM1: 512 blocks = 32bm x 16bn; XCD k owns bm in [4k,4k+4), bn sweeping.
        bm = ((orig & 7) << 2) | ((orig >> 3) & 3);
        bn = orig >> 5;
    } else {
        // bn-inner: each XCD sweeps all bn for a contiguous bm range (A L2-resident)
        const int cpx  = gridDim.x >> 3;
        const int swzb = (orig & 7) * cpx + (orig >> 3);
        bn = swzb % nBN;
        bm = swzb / nBN;
    }
    const int m0 = bm * BM;
    const int n0 = bn * 256;

    // ---- staging descriptors (R5-proven; writes conflict-free) ----
    const _Float16* gptr[8];
    int loff[8];
    #pragma unroll
    for (int i = 0; i < PW; ++i) {
        int p, q;
        if (i < H2 || i >= H1) {
            const bool hi = (i >= H1);
            const int  s  = hi ? (i - H1) : i;
            const int  j  = wave * H2 + s;
            p = j / (CHA / 2);                    // 0=Ah, 1=Al
            const int v   = j % (CHA / 2);
            const int wmq = v / (MI / 2);
            const int wi  = v % (MI / 2);
            q = wmq * MI + (hi ? MI / 2 : 0) + wi;
        } else {
            q = (i - H2) + (wave & 3) * 4;
            p = 2 + (wave >> 2);
        }
        const int row = q*16 + (lane >> 2);
        const int gc  = (lane & 3) ^ ((row >> 1) & 3);
        const _Float16* plane = (p == 0) ? Agh : (p == 1) ? Agl : (p == 2) ? Bgh : Bgl;
        const size_t grow = (size_t)((p < 2) ? m0 : n0) + row;
        gptr[i] = plane + grow * (size_t)K + gc * 8;
        loff[i] = ((p < 2) ? p * ALO : BHO + (p - 2) * 8192) + q * 512;
    }

    // ---- fragment ds_read offsets: zero-conflict 16-row-span pattern ----
    const int swz8 = (fg ^ ((fr >> 1) & 3)) * 8;
    int aoff[MI], boff[4];
    #pragma unroll
    for (int mi = 0; mi < MI; ++mi) aoff[mi] = (wm*WROWS + mi*16 + fr)*32 + swz8;
    #pragma unroll
    for (int ni = 0; ni < 4; ++ni)  boff[ni] = BHO + (wn*64 + ni*16 + fr)*32 + swz8;

    f32x4 acc[MI][4] = {};

    // prologue: stage tile 0
    #pragma unroll
    for (int i = 0; i < PW; ++i) { gload16(gptr[i], &lds[loff[i]]); gptr[i] += 32; }
    VMCNT<0>(); BARRIER(); SB0();

    const int NT = K >> 5;
    int bb = 0;

#define MFMA3(MIdx, NIdx, AH, AL, BH, BL) do {                               \
        acc[MIdx][NIdx] = MFMA16((AH), (BH), acc[MIdx][NIdx], 0, 0, 0);      \
        acc[MIdx][NIdx] = MFMA16((AH), (BL), acc[MIdx][NIdx], 0, 0, 0);      \
        acc[MIdx][NIdx] = MFMA16((AL), (BH), acc[MIdx][NIdx], 0, 0, 0);      \
    } while (0)

#define MFMA12(MIdx, AH, AL) do {                                        \
        acc[MIdx][0] = MFMA16((AH), bh0, acc[MIdx][0], 0, 0, 0);         \
        acc[MIdx][1] = MFMA16((AH), bh1, acc[MIdx][1], 0, 0, 0);         \
        acc[MIdx][2] = MFMA16((AH), bh2, acc[MIdx][2], 0, 0, 0);         \
        acc[MIdx][3] = MFMA16((AH), bh3, acc[MIdx][3], 0, 0, 0);         \
        acc[MIdx][0] = MFMA16((AH), bl0, acc[MIdx][0], 0, 0, 0);         \
        acc[MIdx][1] = MFMA16((AH), bl1, acc[MIdx][1], 0, 0, 0);         \
        acc[MIdx][2] = MFMA16((AH), bl2, acc[MIdx][2], 0, 0, 0);         \
        acc[MIdx][3] = MFMA16((AH), bl3, acc[MIdx][3], 0, 0, 0);         \
        acc[MIdx][0] = MFMA16((AL), bh0, acc[MIdx][0], 0, 0, 0);         \
        acc[MIdx][1] = MFMA16((AL), bh1, acc[MIdx][1], 0, 0, 0);         \
        acc[MIdx][2] = MFMA16((AL), bh2, acc[MIdx][2], 0, 0, 0);         \
        acc[MIdx][3] = MFMA16((AL), bh3, acc[MIdx][3], 0, 0, 0);         \
    } while (0)

// step body: STG = stage next tile into nbuf.
// Emission per SGB: [VMEM xPW][DS 6][DS 4][MFMA 6][DS 2][MFMA 6]{[DS 2][MFMA 12]}...
#define STEP_BODY(STG)                                                            \
    do {                                                                          \
        if (STG) {                                                                \
            _Pragma("unroll")                                                     \
            for (int i = 0; i < PW; ++i) {                                        \
                gload16(gptr[i], &lds[nbuf + loff[i]]); gptr[i] += 32;            \
            }                                                                     \
        }                                                                         \
        f16x8 ah[2], al[2];                                                       \
        f16x8 bh0, bl0, bh1, bl1, bh2, bl2, bh3, bl3;                             \
        /* pre-reads: b0, b1, a0 (consumed by G0/G1) */                           \
        bh0 = *(const f16x8*)&lds[bb + boff[0]];                                  \
        bl0 = *(const f16x8*)&lds[bb + 8192 + boff[0]];                           \
        bh1 = *(const f16x8*)&lds[bb + boff[1]];                                  \
        bl1 = *(const f16x8*)&lds[bb + 8192 + boff[1]];                           \
        ah[0] = *(const f16x8*)&lds[bb + aoff[0]];                                \
        al[0] = *(const f16x8*)&lds[bb + ALO + aoff[0]];                          \
        if (STG) SGB(0x010, PW, 0);                                               \
        SGB(0x100, 6, 0);                                                         \
        __builtin_amdgcn_s_setprio(1);                                            \
        /* G0: read b2,b3 | MFMA mi0 x {n0,n1} */                                 \
        bh2 = *(const f16x8*)&lds[bb + boff[2]];                                  \
        bl2 = *(const f16x8*)&lds[bb + 8192 + boff[2]];                           \
        bh3 = *(const f16x8*)&lds[bb + boff[3]];                                  \
        bl3 = *(const f16x8*)&lds[bb + 8192 + boff[3]];                           \
        MFMA3(0, 0, ah[0], al[0], bh0, bl0);                                      \
        MFMA3(0, 1, ah[0], al[0], bh1, bl1);                                      \
        SGB(0x100, 4, 0);                                                         \
        SGB(0x008, 6, 0);                                                         \
        /* G1: read a1 | MFMA mi0 x {n2,n3} */                                    \
        ah[1] = *(const f16x8*)&lds[bb + aoff[1]];                                \
        al[1] = *(const f16x8*)&lds[bb + ALO + aoff[1]];                          \
        MFMA3(0, 2, ah[0], al[0], bh2, bl2);                                      \
        MFMA3(0, 3, ah[0], al[0], bh3, bl3);                                      \
        SGB(0x100, 2, 0);                                                         \
        SGB(0x008, 6, 0);                                                         \
        /* G2..G(MI): read a(mi+1) | MFMA12(mi) */                                \
        _Pragma("unroll")                                                         \
        for (int mi = 1; mi < MI; ++mi) {                                         \
            if (mi < MI - 1) {                                                    \
                ah[(mi + 1) & 1] = *(const f16x8*)&lds[bb + aoff[mi + 1]];        \
                al[(mi + 1) & 1] = *(const f16x8*)&lds[bb + ALO + aoff[mi + 1]];  \
                SGB(0x100, 2, 0);                                                 \
            }                                                                     \
            MFMA12(mi, ah[mi & 1], al[mi & 1]);                                   \
            SGB(0x008, 12, 0);                                                    \
        }                                                                         \
        __builtin_amdgcn_s_setprio(0);                                            \
    } while (0)

    for (int t = 0; t < NT - 1; ++t) {
        const int nbuf = BUFS - bb;
        STEP_BODY(true);
        VMCNT<0>(); BARRIER(); SB0();
        bb = nbuf;
    }
    {   // peeled last step: no staging
        const int nbuf = 0; (void)nbuf;
        STEP_BODY(false);
    }
#undef STEP_BODY
#undef MFMA12
#undef MFMA3

    // ---- epilogue: bias (+ReLU+split | f32 store) ----
    // 16x16 D mapping (HW-verified): n = lane&15, m = (lane>>4)*4 + reg
    #pragma unroll
    for (int ni = 0; ni < 4; ++ni) {
        const int n = n0 + wn*64 + ni*16 + fr;
        if (!SPLITOUT && n >= Nstore) continue;
        const float bv = bias[n];
        #pragma unroll
        for (int mi = 0; mi < MI; ++mi) {
            #pragma unroll
            for (int j = 0; j < 4; ++j) {
                const int m = m0 + wm*WROWS + mi*16 + fg*4 + j;
                float v = acc[mi][ni][j] + bv;
                if (SPLITOUT) {
                    v = fmaxf(v, 0.f);
                    const _Float16 hh = (_Float16)v;
                    Oh[(size_t)m * ldo + n] = hh;
                    Ol[(size_t)m * ldo + n] = (_Float16)(v - (float)hh);
                } else {
                    Of[(size_t)m * ldo + n] = v;
                }
            }
        }
    }
}

// ================= fallback path (R2, known-passing) =================
#define TILE_M 128
#define TILE_N 128
#define TILE_K 32
#define LDSK   40

template<bool RELU, bool NGUARD>
__global__ __launch_bounds__(256, 2)
void gemm_split3(const float* __restrict__ A, const float* __restrict__ B,
                 const float* __restrict__ bias, float* __restrict__ C,
                 int K, int ldc, int Nreal)
{
    __shared__ _Float16 Ah[TILE_M][LDSK];
    __shared__ _Float16 Al[TILE_M][LDSK];
    __shared__ _Float16 Bh[TILE_N][LDSK];
    __shared__ _Float16 Bl[TILE_N][LDSK];

    const int tid  = threadIdx.x;
    const int lane = tid & 63;
    const int wave = tid >> 6;
    const int wr   = wave >> 1;
    const int wc   = wave & 1;
    const int m0   = blockIdx.x * TILE_M;
    const int n0   = blockIdx.y * TILE_N;
    const int srow = tid >> 3;
    const int scol = (tid & 7) << 2;
    const int fr = lane & 15;
    const int fg = lane >> 4;

    f32x4 acc[4][4] = {};

    for (int kt = 0; kt < K; kt += TILE_K) {
        __syncthreads();
        #pragma unroll
        for (int p = 0; p < 4; ++p) {
            const int row = srow + p * 32;
            f32x4 v = *(const f32x4*)(A + (size_t)(m0 + row) * K + kt + scol);
            f16x4 hv, lv;
            split4(v, hv, lv);
            *(f16x4*)&Ah[row][scol] = hv;
            *(f16x4*)&Al[row][scol] = lv;
        }
        #pragma unroll
        for (int p = 0; p < 4; ++p) {
            const int row = srow + p * 32;
            f32x4 v = {0.f, 0.f, 0.f, 0.f};
            if (!NGUARD || (n0 + row) < Nreal)
                v = *(const f32x4*)(B + (size_t)(n0 + row) * K + kt + scol);
            f16x4 hv, lv;
            split4(v, hv, lv);
            *(f16x4*)&Bh[row][scol] = hv;
            *(f16x4*)&Bl[row][scol] = lv;
        }
        __syncthreads();

        f16x8 ah[4], al[4];
        #pragma unroll
        for (int mi = 0; mi < 4; ++mi) {
            const int r = wr * 64 + mi * 16 + fr;
            ah[mi] = *(const f16x8*)&Ah[r][fg * 8];
            al[mi] = *(const f16x8*)&Al[r][fg * 8];
        }
        #pragma unroll
        for (int ni = 0; ni < 4; ++ni) {
            const int r = wc * 64 + ni * 16 + fr;
            const f16x8 bh = *(const f16x8*)&Bh[r][fg * 8];
            const f16x8 bl = *(const f16x8*)&Bl[r][fg * 8];
            #pragma unroll
            for (int mi = 0; mi < 4; ++mi) {
                acc[mi][ni] = __builtin_amdgcn_mfma_f32_16x16x32_f16(ah[mi], bh, acc[mi][ni], 0, 0, 0);
                acc[mi][ni] = __builtin_amdgcn_mfma_f32_16x16x32_f16(ah[mi], bl, acc[mi][ni], 0, 0, 0);
                acc[mi][ni] = __builtin_amdgcn_mfma_f32_16x16x32_f16(al[mi], bh, acc[mi][ni], 0, 0, 0);
            }
        }
    }

    #pragma unroll
    for (int ni = 0; ni < 4; ++ni) {
        const int n = n0 + wc * 64 + ni * 16 + fr;
        if (NGUARD && n >= Nreal) continue;
        const float bv = bias[n];
        #pragma unroll
        for (int mi = 0; mi < 4; ++mi) {
            #pragma unroll
            for (int j = 0; j < 4; ++j) {
                const int m = m0 + wr * 64 + mi * 16 + fg * 4 + j;
                float val = acc[mi][ni][j] + bv;
                if (RELU) val = fmaxf(val, 0.f);
                C[(size_t)m * ldc + n] = val;
            }
        }
    }
}

// In-place row softmax: one wave per row (cols <= 1024).
__global__ __launch_bounds__(256)
void softmax_rows(float* __restrict__ out, int rows, int cols)
{
    const int lane = threadIdx.x & 63;
    const int row  = blockIdx.x * 4 + (threadIdx.x >> 6);
    if (row >= rows) return;
    float* p = out + (size_t)row * cols;

    float v[16];
    float mx = -3.4e38f;
    #pragma unroll
    for (int j = 0; j < 16; ++j) {
        const int c = lane + j * 64;
        v[j] = (c < cols) ? p[c] : -3.4e38f;
        mx = fmaxf(mx, v[j]);
    }
    #pragma unroll
    for (int off = 32; off > 0; off >>= 1)
        mx = fmaxf(mx, __shfl_xor(mx, off));

    float s = 0.f;
    #pragma unroll
    for (int j = 0; j < 16; ++j) {
        const int c = lane + j * 64;
        const float e = (c < cols) ? __expf(v[j] - mx) : 0.f;
        v[j] = e;
        s += e;
    }
    #pragma unroll
    for (int off = 32; off > 0; off >>= 1)
        s += __shfl_xor(s, off);

    const float inv = 1.f / s;
    #pragma unroll
    for (int j = 0; j < 16; ++j) {
        const int c = lane + j * 64;
        if (c < cols) p[c] = v[j] * inv;
    }
}

// ================= host =================
extern "C" void kernel_launch(void* const* d_in, const int* in_sizes, int n_in,
                              void* d_out, int out_size, void* d_ws, size_t ws_size,
                              hipStream_t stream)
{
    const float* x  = (const float*)d_in[0];   // [8192, 4096]
    const float* w1 = (const float*)d_in[1];   // [4096, 4096]
    const float* b1 = (const float*)d_in[2];   // [4096]
    const float* w2 = (const float*)d_in[3];   // [1000, 4096]
    const float* b2 = (const float*)d_in[4];   // [1000]
    float* out = (float*)d_out;                // [8192, 1000] fp32

    const size_t SZ_X  = (size_t)8192 * 4096 * 2;
    const size_t SZ_W1 = (size_t)4096 * 4096 * 2;
    const size_t SZ_W2 = (size_t)1024 * 4096 * 2;

    size_t off = 0;
    auto take = [&](size_t b) { size_t o = off; off += (b + 255) & ~(size_t)255; return o; };
    const size_t o_xh  = take(SZ_X),  o_xl  = take(SZ_X);
    const size_t o_w1h = take(SZ_W1), o_w1l = take(SZ_W1);
    const size_t o_w2h = take(SZ_W2), o_w2l = take(SZ_W2);
    const size_t o_ah  = take(SZ_X),  o_al  = take(SZ_X);
    const size_t need = off;

    bool attr_ok =
        (hipFuncSetAttribute((const void*)gemm3_v11<8, true, true>,
                             hipFuncAttributeMaxDynamicSharedMemorySize, 131072) == hipSuccess) &&
        (hipFuncSetAttribute((const void*)gemm3_v11<4, false, false>,
                             hipFuncAttributeMaxDynamicSharedMemorySize, 131072) == hipSuccess);

    const dim3 blk256(256, 1, 1), blk512(512, 1, 1);

    if (attr_ok && ws_size >= need) {
        char* w = (char*)d_ws;
        _Float16 *xh  = (_Float16*)(w + o_xh),  *xl  = (_Float16*)(w + o_xl);
        _Float16 *w1h = (_Float16*)(w + o_w1h), *w1l = (_Float16*)(w + o_w1l);
        _Float16 *w2h = (_Float16*)(w + o_w2h), *w2l = (_Float16*)(w + o_w2l);
        _Float16 *ath = (_Float16*)(w + o_ah),  *atl = (_Float16*)(w + o_al);

        hipLaunchKernelGGL(split_rows, dim3(2048), blk256, 0, stream, x,  xh,  xl,  8192, (long long)8192 * 1024);
        hipLaunchKernelGGL(split_rows, dim3(2048), blk256, 0, stream, w1, w1h, w1l, 4096, (long long)4096 * 1024);
        hipLaunchKernelGGL(split_rows, dim3(1024), blk256, 0, stream, w2, w2h, w2l, 1000, (long long)1024 * 1024);

        // GEMM1: act(hi/lo) = relu(x @ w1^T + b1)   M=8192 N=4096 K=4096, BM=256, chunked swizzle
        hipLaunchKernelGGL((gemm3_v11<8, true, true>), dim3(512), blk512, 131072, stream,
                           xh, xl, w1h, w1l, b1, ath, atl, (float*)nullptr, 4096, 4096, 4096, 16);
        // GEMM2: logits = act @ w2^T + b2           M=8192 N=1024(pad) K=4096, BM=128, bn-inner
        hipLaunchKernelGGL((gemm3_v11<4, false, false>), dim3(256), blk512, 98304, stream,
                           ath, atl, w2h, w2l, b2, (_Float16*)nullptr, (_Float16*)nullptr,
                           out, 1000, 1000, 4096, 4);
        hipLaunchKernelGGL(softmax_rows, dim3(2048), blk256, 0, stream, out, 8192, 1000);
    } else {
        float* act = (float*)d_ws;
        hipLaunchKernelGGL((gemm_split3<true, false>), dim3(64, 32), blk256, 0, stream,
                           x, w1, b1, act, 4096, 4096, 4096);
        hipLaunchKernelGGL((gemm_split3<false, true>), dim3(64, 8), blk256, 0, stream,
                           act, w2, b2, out, 4096, 1000, 1000);
        hipLaunchKernelGGL(softmax_rows, dim3(2048), blk256, 0, stream, out, 8192, 1000);
    }
}